// Round 1
// baseline (374.993 us; speedup 1.0000x reference)
//
#include <hip/hip_runtime.h>

typedef short s16x8 __attribute__((ext_vector_type(8)));
typedef float f32x4 __attribute__((ext_vector_type(4)));
typedef float f32x16 __attribute__((ext_vector_type(16)));
typedef unsigned int u32;
typedef unsigned short u16;

#define TOK 216
#define NCH 128
#define NKT 7
#define THREADS 448
#define SP 110592           // 48*48*48
#define BUF0 0              // qb -> kb -> obuf : 224 rows x 256B = 57344
#define VOFF 57344          // vb_t: 128 rows x 512B = 65536 ; later wbuf 128x256B
#define POFF 122880         // per-wave P tiles: 7 x 4096
#define LDS_BYTES 151552

__device__ __forceinline__ u16 f2bf(float f) {
  u32 u = __builtin_bit_cast(u32, f);
  u32 r = u + 0x7FFFu + ((u >> 16) & 1u);
  return (u16)(r >> 16);
}
__device__ __forceinline__ int swz(int row, int inner) {
  return inner ^ ((row & 7) << 4);
}

template<bool TRANSP>
__device__ __forceinline__ void ln_pass(const float* __restrict__ x,
                                        const float* __restrict__ g,
                                        const float* __restrict__ b,
                                        float postScale, char* smem, int dstBase,
                                        int token, int ch0, int gpos) {
  float xv[64];
  const float* p = x + gpos + ch0 * SP;
#pragma unroll
  for (int c = 0; c < 64; ++c) xv[c] = p[c * SP];
  float s = 0.f, s2 = 0.f;
#pragma unroll
  for (int c = 0; c < 64; ++c) { s += xv[c]; s2 += xv[c] * xv[c]; }
  s += __shfl_xor(s, 1);
  s2 += __shfl_xor(s2, 1);
  float mean = s * (1.0f / 128.0f);
  float var = s2 * (1.0f / 128.0f) - mean * mean;
  float rstd = rsqrtf(var + 1e-5f);
#pragma unroll
  for (int c = 0; c < 64; c += 2) {
    int cc = ch0 + c;
    float y0 = ((xv[c]     - mean) * rstd * g[cc]     + b[cc])     * postScale;
    float y1 = ((xv[c + 1] - mean) * rstd * g[cc + 1] + b[cc + 1]) * postScale;
    if (TRANSP) {
      *(u16*)(smem + dstBase + cc * 512       + swz(cc,     token * 2)) = f2bf(y0);
      *(u16*)(smem + dstBase + (cc + 1) * 512 + swz(cc + 1, token * 2)) = f2bf(y1);
    } else {
      u32 pk = (u32)f2bf(y0) | ((u32)f2bf(y1) << 16);
      *(u32*)(smem + dstBase + token * 256 + swz(token, cc * 2)) = pk;
    }
  }
}

extern "C" __global__ __launch_bounds__(THREADS)
void ca3d_kernel(const float* __restrict__ qm, const float* __restrict__ km,
                 const float* __restrict__ vm,
                 const float* __restrict__ gq, const float* __restrict__ bq,
                 const float* __restrict__ gkv, const float* __restrict__ bkv,
                 const float* __restrict__ pw, const float* __restrict__ pb,
                 float* __restrict__ out) {
  extern __shared__ __align__(16) char smem[];
  const int tid = threadIdx.x;
  const int lane = tid & 63;
  const int wv = tid >> 6;
  const int wid = blockIdx.x;
  const int wd = wid >> 6, wh = (wid >> 3) & 7, ww = wid & 7;
  const int boff = wd * 6 * 2304 + wh * 6 * 48 + ww * 6;

  // zero qb/kb + vb_t regions (pad rows must be finite/zero)
  for (int i = tid * 16; i < VOFF + 65536; i += THREADS * 16)
    *(f32x4*)(smem + i) = (f32x4){};
  __syncthreads();

  const bool lnAct = tid < 432;
  const int token = tid >> 1;
  const int ch0 = (tid & 1) * 64;
  int td = token / 36, tr_ = token - td * 36;
  int th_ = tr_ / 6, tw_ = tr_ - th_ * 6;
  const int gpos = boff + td * 2304 + th_ * 48 + tw_;

  // ---- Q layernorm (scale 0.25 folded) -> buf0
  if (lnAct) ln_pass<false>(qm, gq, bq, 0.25f, smem, BUF0, token, ch0, gpos);
  __syncthreads();

  // ---- Q fragments to registers (B-operand of swapped QK^T)
  s16x8 qf[8];
  {
    int row = wv * 32 + (lane & 31);
    int ib = (lane >> 5) * 16;
#pragma unroll
    for (int h = 0; h < 8; ++h)
      qf[h] = *(const s16x8*)(smem + BUF0 + row * 256 + swz(row, h * 32 + ib));
  }
  __syncthreads();

  // ---- K -> buf0 (overwrite), V -> vb_t (transposed)
  if (lnAct) {
    ln_pass<false>(km, gkv, bkv, 1.0f, smem, BUF0, token, ch0, gpos);
    ln_pass<true >(vm, gkv, bkv, 1.0f, smem, VOFF, token, ch0, gpos);
  }
  __syncthreads();

  // ---- attention: wave wv owns q rows [wv*32, wv*32+32)
  u32 oPk[8][4];
  const int pbase = POFF + wv * 4096;
  const int qcol = lane & 31;
  const int half = lane >> 5;
#pragma unroll
  for (int h = 0; h < 8; ++h) {
    f32x4 o0 = {}; f32x4 o1 = {};
    float m = -1e30f, lsum = 0.f;
#pragma unroll 1
    for (int kt = 0; kt < NKT; ++kt) {
      int krow = kt * 32 + (lane & 31);
      s16x8 kf = *(const s16x8*)(smem + BUF0 + krow * 256 +
                                 swz(krow, h * 32 + half * 16));
      f32x16 st = {};
      st = __builtin_amdgcn_mfma_f32_32x32x16_bf16(kf, qf[h], st, 0, 0, 0);
      float sv[16];
#pragma unroll
      for (int r = 0; r < 16; ++r) {
        int kl = (r & 3) + 8 * (r >> 2) + 4 * half;
        sv[r] = (kt * 32 + kl < TOK) ? st[r] : -1e30f;
      }
      float pmax = sv[0];
#pragma unroll
      for (int r = 1; r < 16; ++r) pmax = fmaxf(pmax, sv[r]);
      pmax = fmaxf(pmax, __shfl_xor(pmax, 32));
      float mn = fmaxf(m, pmax);
      float fct = __expf(m - mn);
      float pv[16];
      float ts = 0.f;
#pragma unroll
      for (int r = 0; r < 16; ++r) { pv[r] = __expf(sv[r] - mn); ts += pv[r]; }
      lsum = lsum * fct + ts;
      m = mn;
#pragma unroll
      for (int r = 0; r < 4; ++r) {
        o0[r] *= __shfl(fct, (lane >> 4) * 4 + r);
        o1[r] *= __shfl(fct, 16 + (lane >> 4) * 4 + r);
      }
      // P (bf16) -> per-wave LDS tile, transposing to [q][k]
#pragma unroll
      for (int r = 0; r < 16; r += 2) {
        int k0 = (r & 3) + 8 * (r >> 2) + 4 * half;
        u32 pk = (u32)f2bf(pv[r]) | ((u32)f2bf(pv[r + 1]) << 16);
        *(u32*)(smem + pbase + qcol * 128 + swz(qcol, k0 * 2)) = pk;
      }
      // PV
      int vrow = h * 16 + (lane & 15);
      s16x8 vf = *(const s16x8*)(smem + VOFF + vrow * 512 +
                                 swz(vrow, kt * 64 + (lane >> 4) * 16));
      s16x8 pa0 = *(const s16x8*)(smem + pbase + (lane & 15) * 128 +
                                  swz(lane & 15, (lane >> 4) * 16));
      s16x8 pa1 = *(const s16x8*)(smem + pbase + (16 + (lane & 15)) * 128 +
                                  swz(16 + (lane & 15), (lane >> 4) * 16));
      o0 = __builtin_amdgcn_mfma_f32_16x16x32_bf16(pa0, vf, o0, 0, 0, 0);
      o1 = __builtin_amdgcn_mfma_f32_16x16x32_bf16(pa1, vf, o1, 0, 0, 0);
    }
    lsum += __shfl_xor(lsum, 32);
    float linv = 1.0f / lsum;
#pragma unroll
    for (int r = 0; r < 4; ++r) {
      o0[r] *= __shfl(linv, (lane >> 4) * 4 + r);
      o1[r] *= __shfl(linv, 16 + (lane >> 4) * 4 + r);
    }
    oPk[h][0] = (u32)f2bf(o0[0]) | ((u32)f2bf(o0[1]) << 16);
    oPk[h][1] = (u32)f2bf(o0[2]) | ((u32)f2bf(o0[3]) << 16);
    oPk[h][2] = (u32)f2bf(o1[0]) | ((u32)f2bf(o1[1]) << 16);
    oPk[h][3] = (u32)f2bf(o1[2]) | ((u32)f2bf(o1[3]) << 16);
  }
  __syncthreads();

  // ---- O -> obuf (buf0, bf16) ; proj_w -> wbuf (vb_t region, bf16)
#pragma unroll
  for (int h = 0; h < 8; ++h) {
#pragma unroll
    for (int j = 0; j < 8; ++j) {
      int qh = j >> 2, r = j & 3;
      int row = wv * 32 + qh * 16 + (lane >> 4) * 4 + r;
      int c = h * 16 + (lane & 15);
      u16 v = (u16)(oPk[h][qh * 2 + (r >> 1)] >> ((r & 1) * 16));
      *(u16*)(smem + BUF0 + row * 256 + swz(row, c * 2)) = v;
    }
  }
  for (int i = tid; i < 16384; i += THREADS) {
    int j = i >> 7, c = i & 127;
    *(u16*)(smem + VOFF + j * 256 + swz(j, c * 2)) = f2bf(pw[i]);
  }
  __syncthreads();

  // ---- projection + store
#pragma unroll 1
  for (int th2 = 0; th2 < 2; ++th2) {
    int rowA = wv * 32 + th2 * 16 + (lane & 15);
#pragma unroll 1
    for (int jt = 0; jt < 8; ++jt) {
      f32x4 acc = {};
#pragma unroll
      for (int kk = 0; kk < 4; ++kk) {
        s16x8 af = *(const s16x8*)(smem + BUF0 + rowA * 256 +
                                   swz(rowA, kk * 64 + (lane >> 4) * 16));
        int rowB = jt * 16 + (lane & 15);
        s16x8 bfr = *(const s16x8*)(smem + VOFF + rowB * 256 +
                                    swz(rowB, kk * 64 + (lane >> 4) * 16));
        acc = __builtin_amdgcn_mfma_f32_16x16x32_bf16(af, bfr, acc, 0, 0, 0);
      }
      int j = jt * 16 + (lane & 15);
      float bias = pb[j];
#pragma unroll
      for (int r = 0; r < 4; ++r) {
        int tokIdx = wv * 32 + th2 * 16 + (lane >> 4) * 4 + r;
        if (tokIdx < TOK) {
          int tdd = tokIdx / 36, trr = tokIdx - tdd * 36;
          int thh = trr / 6, tww = trr - thh * 6;
          out[j * SP + boff + tdd * 2304 + thh * 48 + tww] = acc[r] + bias;
        }
      }
    }
  }
}

extern "C" void kernel_launch(void* const* d_in, const int* in_sizes, int n_in,
                              void* d_out, int out_size, void* d_ws, size_t ws_size,
                              hipStream_t stream) {
  const float* qm  = (const float*)d_in[0];
  const float* km  = (const float*)d_in[1];
  const float* vm  = (const float*)d_in[2];
  const float* gq  = (const float*)d_in[3];
  const float* bq  = (const float*)d_in[4];
  const float* gkv = (const float*)d_in[5];
  const float* bkv = (const float*)d_in[6];
  const float* pw  = (const float*)d_in[7];
  const float* pb  = (const float*)d_in[8];
  hipLaunchKernelGGL(ca3d_kernel, dim3(512), dim3(THREADS), LDS_BYTES, stream,
                     qm, km, vm, gq, bq, gkv, bkv, pw, pb, (float*)d_out);
}

// Round 2
// 181.134 us; speedup vs baseline: 2.0703x; 2.0703x over previous
//
#include <hip/hip_runtime.h>

typedef short s16x8 __attribute__((ext_vector_type(8)));
typedef float f32x2 __attribute__((ext_vector_type(2)));
typedef float f32x4 __attribute__((ext_vector_type(4)));
typedef float f32x16 __attribute__((ext_vector_type(16)));
typedef unsigned int u32;
typedef unsigned short u16;

#define TOK 216
#define NKT 7
#define THREADS 448
#define SP 110592           // 48*48*48
#define BUF0 0              // qb -> kb -> obuf : 224 rows x 256B = 57344
#define VOFF 57344          // vb_t: 128 rows x 512B = 65536 ; later wbuf 128x256B
#define POFF 122880         // gamma/beta staging (2KB), then per-wave P tiles 7x4096
#define LDS_BYTES 151552

__device__ __forceinline__ u16 f2bf(float f) {
  u32 u = __builtin_bit_cast(u32, f);
  u32 r = u + 0x7FFFu + ((u >> 16) & 1u);
  return (u16)(r >> 16);
}
__device__ __forceinline__ u32 pack2(float a, float b) {
  return (u32)f2bf(a) | ((u32)f2bf(b) << 16);
}
__device__ __forceinline__ int swz(int row, int inner) {
  return inner ^ ((row & 7) << 4);
}

// per token-pair LN stats over 128 ch held as 32 f32x2 across 4 lanes
__device__ __forceinline__ void ln_stats(const f32x2* xv, float& mA, float& rA,
                                         float& mB, float& rB) {
  float sA = 0.f, s2A = 0.f, sB = 0.f, s2B = 0.f;
#pragma unroll
  for (int c = 0; c < 32; ++c) {
    sA += xv[c].x; s2A += xv[c].x * xv[c].x;
    sB += xv[c].y; s2B += xv[c].y * xv[c].y;
  }
  sA += __shfl_xor(sA, 1); s2A += __shfl_xor(s2A, 1);
  sB += __shfl_xor(sB, 1); s2B += __shfl_xor(s2B, 1);
  sA += __shfl_xor(sA, 2); s2A += __shfl_xor(s2A, 2);
  sB += __shfl_xor(sB, 2); s2B += __shfl_xor(s2B, 2);
  mA = sA * (1.0f / 128.0f);
  rA = rsqrtf(s2A * (1.0f / 128.0f) - mA * mA + 1e-5f);
  mB = sB * (1.0f / 128.0f);
  rB = rsqrtf(s2B * (1.0f / 128.0f) - mB * mB + 1e-5f);
}

extern "C" __global__ __launch_bounds__(THREADS, 2)
void ca3d_kernel(const float* __restrict__ qm, const float* __restrict__ km,
                 const float* __restrict__ vm,
                 const float* __restrict__ gq, const float* __restrict__ bq,
                 const float* __restrict__ gkv, const float* __restrict__ bkv,
                 const float* __restrict__ pw, const float* __restrict__ pb,
                 float* __restrict__ out) {
  extern __shared__ __align__(16) char smem[];
  const int tid = threadIdx.x;
  const int lane = tid & 63;
  const int wv = tid >> 6;
  // XCD chunked swizzle: each XCD gets a contiguous 64-window chunk so the 8
  // ww-neighbors sharing each 64B line are co-resident in one L2.
  const int bid = blockIdx.x;
  const int wid = ((bid & 7) << 6) | (bid >> 3);
  const int wd = wid >> 6, wh = (wid >> 3) & 7, ww = wid & 7;
  const int boff = wd * 6 * 2304 + wh * 6 * 48 + ww * 6;

  // zero qb/kb + vb_t regions (pad rows must be finite/zero)
  for (int i = tid * 16; i < VOFF + 65536; i += THREADS * 16)
    *(f32x4*)(smem + i) = (f32x4){};
  // stage gamma/beta in LDS (P region, dead until attention)
  if (tid < 128) {
    ((float*)(smem + POFF))[tid] = gq[tid];
    ((float*)(smem + POFF + 512))[tid] = bq[tid];
    ((float*)(smem + POFF + 1024))[tid] = gkv[tid];
    ((float*)(smem + POFF + 1536))[tid] = bkv[tid];
  }

  // LN thread mapping: 432 threads = 108 token-pairs x 4 channel-quadrants
  const bool lnAct = tid < 432;
  const int tp = tid >> 2;          // token pair
  const int cbase = (tid & 3) * 32; // channel quadrant
  const int tA = tp * 2, tB = tA + 1;
  int td = tA / 36, tr_ = tA - td * 36;
  int th_ = tr_ / 6, tw_ = tr_ - th_ * 6;
  const int gpos = boff + td * 2304 + th_ * 48 + tw_; // tw_ even -> 8B aligned

  f32x2 qv[32], kv[32], vv[32];
  if (lnAct) {
#pragma unroll
    for (int c = 0; c < 32; ++c)
      qv[c] = *(const f32x2*)(qm + gpos + (cbase + c) * SP);
#pragma unroll
    for (int c = 0; c < 32; ++c)
      kv[c] = *(const f32x2*)(km + gpos + (cbase + c) * SP);
  }
  __syncthreads();

  const float* gql = (const float*)(smem + POFF);
  const float* bql = (const float*)(smem + POFF + 512);
  const float* gkl = (const float*)(smem + POFF + 1024);
  const float* bkl = (const float*)(smem + POFF + 1536);

  // ---- Q layernorm (scale 0.25 folded) -> buf0 [token][ch]
  if (lnAct) {
    float mA, rA, mB, rB;
    ln_stats(qv, mA, rA, mB, rB);
#pragma unroll
    for (int c = 0; c < 32; c += 2) {
      int cc = cbase + c;
      float g0 = gql[cc], g1 = gql[cc + 1], b0 = bql[cc], b1 = bql[cc + 1];
      *(u32*)(smem + BUF0 + tA * 256 + swz(tA, cc * 2)) =
          pack2(((qv[c].x - mA) * rA * g0 + b0) * 0.25f,
                ((qv[c + 1].x - mA) * rA * g1 + b1) * 0.25f);
      *(u32*)(smem + BUF0 + tB * 256 + swz(tB, cc * 2)) =
          pack2(((qv[c].y - mB) * rB * g0 + b0) * 0.25f,
                ((qv[c + 1].y - mB) * rB * g1 + b1) * 0.25f);
    }
    // issue V loads now; they complete under the Q-fragment phase
#pragma unroll
    for (int c = 0; c < 32; ++c)
      vv[c] = *(const f32x2*)(vm + gpos + (cbase + c) * SP);
  }
  __syncthreads();

  // ---- Q fragments to registers (B-operand of swapped QK^T)
  s16x8 qf[8];
  {
    int row = wv * 32 + (lane & 31);
    int ib = (lane >> 5) * 16;
#pragma unroll
    for (int h = 0; h < 8; ++h)
      qf[h] = *(const s16x8*)(smem + BUF0 + row * 256 + swz(row, h * 32 + ib));
  }
  __syncthreads();

  // ---- K -> buf0 (overwrite) [token][ch], V -> vb_t [ch][token]
  if (lnAct) {
    {
      float mA, rA, mB, rB;
      ln_stats(kv, mA, rA, mB, rB);
#pragma unroll
      for (int c = 0; c < 32; c += 2) {
        int cc = cbase + c;
        float g0 = gkl[cc], g1 = gkl[cc + 1], b0 = bkl[cc], b1 = bkl[cc + 1];
        *(u32*)(smem + BUF0 + tA * 256 + swz(tA, cc * 2)) =
            pack2((kv[c].x - mA) * rA * g0 + b0,
                  (kv[c + 1].x - mA) * rA * g1 + b1);
        *(u32*)(smem + BUF0 + tB * 256 + swz(tB, cc * 2)) =
            pack2((kv[c].y - mB) * rB * g0 + b0,
                  (kv[c + 1].y - mB) * rB * g1 + b1);
      }
    }
    {
      float mA, rA, mB, rB;
      ln_stats(vv, mA, rA, mB, rB);
#pragma unroll
      for (int c = 0; c < 32; ++c) {
        int cc = cbase + c;
        float g0 = gkl[cc], b0 = bkl[cc];
        *(u32*)(smem + VOFF + cc * 512 + swz(cc, tA * 2)) =
            pack2((vv[c].x - mA) * rA * g0 + b0,
                  (vv[c].y - mB) * rB * g0 + b0);
      }
    }
  }
  __syncthreads();

  // ---- attention: wave wv owns q rows [wv*32, wv*32+32)
  u32 oPk[8][4];
  const int pbase = POFF + wv * 4096;
  const int qcol = lane & 31;
  const int half = lane >> 5;
#pragma unroll
  for (int h = 0; h < 8; ++h) {
    f32x4 o0 = {}; f32x4 o1 = {};
    float m = -1e30f, lsum = 0.f;
#pragma unroll 1
    for (int kt = 0; kt < NKT; ++kt) {
      int krow = kt * 32 + (lane & 31);
      s16x8 kf = *(const s16x8*)(smem + BUF0 + krow * 256 +
                                 swz(krow, h * 32 + half * 16));
      f32x16 st = {};
      st = __builtin_amdgcn_mfma_f32_32x32x16_bf16(kf, qf[h], st, 0, 0, 0);
      float sv[16];
#pragma unroll
      for (int r = 0; r < 16; ++r) {
        int kl = (r & 3) + 8 * (r >> 2) + 4 * half;
        sv[r] = (kt * 32 + kl < TOK) ? st[r] : -1e30f;
      }
      float pmax = sv[0];
#pragma unroll
      for (int r = 1; r < 16; ++r) pmax = fmaxf(pmax, sv[r]);
      pmax = fmaxf(pmax, __shfl_xor(pmax, 32));
      float mn = fmaxf(m, pmax);
      float fct = __expf(m - mn);
      float pv[16];
      float ts = 0.f;
#pragma unroll
      for (int r = 0; r < 16; ++r) { pv[r] = __expf(sv[r] - mn); ts += pv[r]; }
      lsum = lsum * fct + ts;
      m = mn;
#pragma unroll
      for (int r = 0; r < 4; ++r) {
        o0[r] *= __shfl(fct, (lane >> 4) * 4 + r);
        o1[r] *= __shfl(fct, 16 + (lane >> 4) * 4 + r);
      }
      // P (bf16) -> per-wave LDS tile, transposing to [q][k]
#pragma unroll
      for (int r = 0; r < 16; r += 2) {
        int k0 = (r & 3) + 8 * (r >> 2) + 4 * half;
        *(u32*)(smem + pbase + qcol * 128 + swz(qcol, k0 * 2)) =
            pack2(pv[r], pv[r + 1]);
      }
      // PV
      int vrow = h * 16 + (lane & 15);
      s16x8 vf = *(const s16x8*)(smem + VOFF + vrow * 512 +
                                 swz(vrow, kt * 64 + (lane >> 4) * 16));
      s16x8 pa0 = *(const s16x8*)(smem + pbase + (lane & 15) * 128 +
                                  swz(lane & 15, (lane >> 4) * 16));
      s16x8 pa1 = *(const s16x8*)(smem + pbase + (16 + (lane & 15)) * 128 +
                                  swz(16 + (lane & 15), (lane >> 4) * 16));
      o0 = __builtin_amdgcn_mfma_f32_16x16x32_bf16(pa0, vf, o0, 0, 0, 0);
      o1 = __builtin_amdgcn_mfma_f32_16x16x32_bf16(pa1, vf, o1, 0, 0, 0);
    }
    lsum += __shfl_xor(lsum, 32);
    float linv = 1.0f / lsum;
#pragma unroll
    for (int r = 0; r < 4; ++r) {
      o0[r] *= __shfl(linv, (lane >> 4) * 4 + r);
      o1[r] *= __shfl(linv, 16 + (lane >> 4) * 4 + r);
    }
    oPk[h][0] = pack2(o0[0], o0[1]);
    oPk[h][1] = pack2(o0[2], o0[3]);
    oPk[h][2] = pack2(o1[0], o1[1]);
    oPk[h][3] = pack2(o1[2], o1[3]);
  }
  __syncthreads();

  // ---- O -> buf0 [token][ch] bf16 ; proj_w -> VOFF [j][ch] bf16
#pragma unroll
  for (int h = 0; h < 8; ++h) {
#pragma unroll
    for (int j = 0; j < 8; ++j) {
      int qh = j >> 2, r = j & 3;
      int row = wv * 32 + qh * 16 + (lane >> 4) * 4 + r;
      int c = h * 16 + (lane & 15);
      u16 v = (u16)(oPk[h][qh * 2 + (r >> 1)] >> ((r & 1) * 16));
      *(u16*)(smem + BUF0 + row * 256 + swz(row, c * 2)) = v;
    }
  }
  for (int i = tid; i < 8192; i += THREADS) {
    int j = i >> 6, c2 = i & 63;
    f32x2 w2 = *(const f32x2*)(pw + j * 128 + c2 * 2);
    *(u32*)(smem + VOFF + j * 256 + swz(j, c2 * 4)) = pack2(w2.x, w2.y);
  }
  __syncthreads();

  // ---- projection: D[j][token] = W(A) x O(B); wave owns 2 token tiles
#pragma unroll 1
  for (int ti = 0; ti < 2; ++ti) {
    int tt = wv * 2 + ti;
    int tok = tt * 16 + (lane & 15);
    s16x8 bfr[4];
#pragma unroll
    for (int kk = 0; kk < 4; ++kk)
      bfr[kk] = *(const s16x8*)(smem + BUF0 + tok * 256 +
                                swz(tok, kk * 64 + (lane >> 4) * 16));
    bool tokValid = tok < TOK;
    int tdd = tok / 36, trr = tok - tdd * 36;
    int thh = trr / 6, tww = trr - thh * 6;
    int pos = boff + tdd * 2304 + thh * 48 + tww;
#pragma unroll 1
    for (int jt = 0; jt < 8; ++jt) {
      f32x4 acc = {};
#pragma unroll
      for (int kk = 0; kk < 4; ++kk) {
        int rw = jt * 16 + (lane & 15);
        s16x8 af = *(const s16x8*)(smem + VOFF + rw * 256 +
                                   swz(rw, kk * 64 + (lane >> 4) * 16));
        acc = __builtin_amdgcn_mfma_f32_16x16x32_bf16(af, bfr[kk], acc, 0, 0, 0);
      }
      f32x4 pbv = *(const f32x4*)(pb + jt * 16 + (lane >> 4) * 4);
      if (tokValid) {
#pragma unroll
        for (int r = 0; r < 4; ++r) {
          int j = jt * 16 + (lane >> 4) * 4 + r;
          out[j * SP + pos] = acc[r] + pbv[r];
        }
      }
    }
  }
}

extern "C" void kernel_launch(void* const* d_in, const int* in_sizes, int n_in,
                              void* d_out, int out_size, void* d_ws, size_t ws_size,
                              hipStream_t stream) {
  const float* qm  = (const float*)d_in[0];
  const float* km  = (const float*)d_in[1];
  const float* vm  = (const float*)d_in[2];
  const float* gq  = (const float*)d_in[3];
  const float* bq  = (const float*)d_in[4];
  const float* gkv = (const float*)d_in[5];
  const float* bkv = (const float*)d_in[6];
  const float* pw  = (const float*)d_in[7];
  const float* pb  = (const float*)d_in[8];
  hipLaunchKernelGGL(ca3d_kernel, dim3(512), dim3(THREADS), LDS_BYTES, stream,
                     qm, km, vm, gq, bq, gkv, bkv, pw, pb, (float*)d_out);
}

// Round 4
// 179.763 us; speedup vs baseline: 2.0860x; 1.0076x over previous
//
#include <hip/hip_runtime.h>

typedef short s16x8 __attribute__((ext_vector_type(8)));
typedef float f32x2 __attribute__((ext_vector_type(2)));
typedef float f32x4 __attribute__((ext_vector_type(4)));
typedef float f32x16 __attribute__((ext_vector_type(16)));
typedef unsigned int u32;
typedef unsigned short u16;

#define TOK 216
#define THREADS 448
#define SP 110592           // 48*48*48
#define BUF0 0              // qb -> kb -> obuf : 224 rows x 256B = 57344
#define VOFF 57344          // vb_t: 128 ch-rows x 512B = 65536 ; later wbuf
#define POFF 122880         // per-wave paired-P tiles: 7 x 4096 = 28672
#define GBOFF 151552        // gamma/beta staging: 2048
#define LDS_BYTES 153600

__device__ __forceinline__ u16 f2bf(float f) {
  u32 u = __builtin_bit_cast(u32, f);
  u32 r = u + 0x7FFFu + ((u >> 16) & 1u);
  return (u16)(r >> 16);
}
__device__ __forceinline__ u32 pack2(float a, float b) {
  return (u32)f2bf(a) | ((u32)f2bf(b) << 16);
}
__device__ __forceinline__ int swz(int row, int inner) {
  return inner ^ ((row & 7) << 4);
}

// per token-pair LN stats over 128 ch held as 32 f32x2 across 4 lanes
__device__ __forceinline__ void ln_stats(const f32x2* xv, float& mA, float& rA,
                                         float& mB, float& rB) {
  float sA = 0.f, s2A = 0.f, sB = 0.f, s2B = 0.f;
#pragma unroll
  for (int c = 0; c < 32; ++c) {
    sA += xv[c].x; s2A += xv[c].x * xv[c].x;
    sB += xv[c].y; s2B += xv[c].y * xv[c].y;
  }
  sA += __shfl_xor(sA, 1); s2A += __shfl_xor(s2A, 1);
  sB += __shfl_xor(sB, 1); s2B += __shfl_xor(s2B, 1);
  sA += __shfl_xor(sA, 2); s2A += __shfl_xor(s2A, 2);
  sB += __shfl_xor(sB, 2); s2B += __shfl_xor(s2B, 2);
  mA = sA * (1.0f / 128.0f);
  rA = rsqrtf(s2A * (1.0f / 128.0f) - mA * mA + 1e-5f);
  mB = sB * (1.0f / 128.0f);
  rB = rsqrtf(s2B * (1.0f / 128.0f) - mB * mB + 1e-5f);
}

// QK^T (swapped) + online softmax + P write into head-half hh of the wave's
// shared P tile. Returns the rescale factor for this tile.
__device__ __forceinline__ float qk_soft(const char* smem, int h, int hh, int kt,
                                         s16x8 qfh, int lane, int pbase,
                                         float& m, float& lsum) {
  const int half = lane >> 5;
  const int qcol = lane & 31;
  const int krow = kt * 32 + qcol;
  s16x8 kf = *(const s16x8*)(smem + BUF0 + krow * 256 +
                             swz(krow, h * 32 + half * 16));
  __builtin_amdgcn_s_setprio(1);
  f32x16 st = __builtin_amdgcn_mfma_f32_32x32x16_bf16(kf, qfh, (f32x16){}, 0, 0, 0);
  __builtin_amdgcn_s_setprio(0);
  float sv[16];
#pragma unroll
  for (int r = 0; r < 16; ++r) {
    int kl = (r & 3) + 8 * (r >> 2) + 4 * half;
    sv[r] = (kt * 32 + kl < TOK) ? st[r] : -1e30f;
  }
  float pmax = sv[0];
#pragma unroll
  for (int r = 1; r < 16; ++r) pmax = fmaxf(pmax, sv[r]);
  pmax = fmaxf(pmax, __shfl_xor(pmax, 32));
  float mn = fmaxf(m, pmax);
  float fct = __expf(m - mn);
  m = mn;
  float pvv[16];
  float ts = 0.f;
#pragma unroll
  for (int r = 0; r < 16; ++r) { pvv[r] = __expf(sv[r] - mn); ts += pvv[r]; }
  lsum = lsum * fct + ts;
#pragma unroll
  for (int r = 0; r < 16; r += 2) {
    int k0 = (r & 3) + 8 * (r >> 2) + 4 * half;
    *(u32*)(smem + pbase + qcol * 128 + swz(qcol, hh * 64 + k0 * 2)) =
        pack2(pvv[r], pvv[r + 1]);
  }
  return fct;
}

// Rescale O by fct, then O += P x V for this k-tile.
__device__ __forceinline__ void pv_step(const char* smem, int h, int hh, int kt,
                                        int lane, int pbase, float fct,
                                        f32x4& o0, f32x4& o1) {
#pragma unroll
  for (int r = 0; r < 4; ++r) {
    o0[r] *= __shfl(fct, (lane >> 4) * 4 + r);
    o1[r] *= __shfl(fct, 16 + (lane >> 4) * 4 + r);
  }
  int vrow = h * 16 + (lane & 15);
  s16x8 vf = *(const s16x8*)(smem + VOFF + vrow * 512 +
                             swz(vrow, kt * 64 + (lane >> 4) * 16));
  s16x8 pa0 = *(const s16x8*)(smem + pbase + (lane & 15) * 128 +
                              swz(lane & 15, hh * 64 + (lane >> 4) * 16));
  s16x8 pa1 = *(const s16x8*)(smem + pbase + (16 + (lane & 15)) * 128 +
                              swz(16 + (lane & 15), hh * 64 + (lane >> 4) * 16));
  __builtin_amdgcn_s_setprio(1);
  o0 = __builtin_amdgcn_mfma_f32_16x16x32_bf16(pa0, vf, o0, 0, 0, 0);
  o1 = __builtin_amdgcn_mfma_f32_16x16x32_bf16(pa1, vf, o1, 0, 0, 0);
  __builtin_amdgcn_s_setprio(0);
}

extern "C" __global__ __launch_bounds__(THREADS, 2)
void ca3d_kernel(const float* __restrict__ qm, const float* __restrict__ km,
                 const float* __restrict__ vm,
                 const float* __restrict__ gq, const float* __restrict__ bq,
                 const float* __restrict__ gkv, const float* __restrict__ bkv,
                 const float* __restrict__ pw, const float* __restrict__ pb,
                 float* __restrict__ out) {
  extern __shared__ __align__(16) char smem[];
  const int tid = threadIdx.x;
  const int lane = tid & 63;
  const int wv = tid >> 6;
  // XCD chunked swizzle: contiguous 64-window chunk per XCD
  const int bid = blockIdx.x;
  const int wid = ((bid & 7) << 6) | (bid >> 3);
  const int wd = wid >> 6, wh = (wid >> 3) & 7, ww = wid & 7;
  const int boff = wd * 6 * 2304 + wh * 6 * 48 + ww * 6;

  // zero qb/kb + vb_t regions (pad rows must be finite/zero)
  for (int i = tid * 16; i < VOFF + 65536; i += THREADS * 16)
    *(f32x4*)(smem + i) = (f32x4){};
  if (tid < 128) {
    ((float*)(smem + GBOFF))[tid] = gq[tid];
    ((float*)(smem + GBOFF + 512))[tid] = bq[tid];
    ((float*)(smem + GBOFF + 1024))[tid] = gkv[tid];
    ((float*)(smem + GBOFF + 1536))[tid] = bkv[tid];
  }

  // LN thread mapping: 432 threads = 108 token-pairs x 4 channel-quadrants
  const bool lnAct = tid < 432;
  const int tp = tid >> 2;
  const int cbase = (tid & 3) * 32;
  const int tA = tp * 2, tB = tA + 1;
  int td = tA / 36, tr_ = tA - td * 36;
  int th_ = tr_ / 6, tw_ = tr_ - th_ * 6;
  const int gpos = boff + td * 2304 + th_ * 48 + tw_;

  f32x2 qv[32], kv[32], vv[32];
  if (lnAct) {
#pragma unroll
    for (int c = 0; c < 32; ++c)
      qv[c] = *(const f32x2*)(qm + gpos + (cbase + c) * SP);
#pragma unroll
    for (int c = 0; c < 32; ++c)
      kv[c] = *(const f32x2*)(km + gpos + (cbase + c) * SP);
  }
  __syncthreads();

  const float* gql = (const float*)(smem + GBOFF);
  const float* bql = (const float*)(smem + GBOFF + 512);
  const float* gkl = (const float*)(smem + GBOFF + 1024);
  const float* bkl = (const float*)(smem + GBOFF + 1536);

  // ---- Q layernorm (scale 0.25 folded) -> buf0 [token][ch]
  if (lnAct) {
    float mA, rA, mB, rB;
    ln_stats(qv, mA, rA, mB, rB);
#pragma unroll
    for (int c = 0; c < 32; c += 2) {
      int cc = cbase + c;
      float g0 = gql[cc], g1 = gql[cc + 1], b0 = bql[cc], b1 = bql[cc + 1];
      *(u32*)(smem + BUF0 + tA * 256 + swz(tA, cc * 2)) =
          pack2(((qv[c].x - mA) * rA * g0 + b0) * 0.25f,
                ((qv[c + 1].x - mA) * rA * g1 + b1) * 0.25f);
      *(u32*)(smem + BUF0 + tB * 256 + swz(tB, cc * 2)) =
          pack2(((qv[c].y - mB) * rB * g0 + b0) * 0.25f,
                ((qv[c + 1].y - mB) * rB * g1 + b1) * 0.25f);
    }
#pragma unroll
    for (int c = 0; c < 32; ++c)
      vv[c] = *(const f32x2*)(vm + gpos + (cbase + c) * SP);
  }
  __syncthreads();

  // ---- Q fragments to registers (B-operand of swapped QK^T)
  s16x8 qf[8];
  {
    int row = wv * 32 + (lane & 31);
    int ib = (lane >> 5) * 16;
#pragma unroll
    for (int h = 0; h < 8; ++h)
      qf[h] = *(const s16x8*)(smem + BUF0 + row * 256 + swz(row, h * 32 + ib));
  }
  __syncthreads();

  // ---- K -> buf0 (overwrite) [token][ch], V -> vb_t [ch][token]
  if (lnAct) {
    {
      float mA, rA, mB, rB;
      ln_stats(kv, mA, rA, mB, rB);
#pragma unroll
      for (int c = 0; c < 32; c += 2) {
        int cc = cbase + c;
        float g0 = gkl[cc], g1 = gkl[cc + 1], b0 = bkl[cc], b1 = bkl[cc + 1];
        *(u32*)(smem + BUF0 + tA * 256 + swz(tA, cc * 2)) =
            pack2((kv[c].x - mA) * rA * g0 + b0,
                  (kv[c + 1].x - mA) * rA * g1 + b1);
        *(u32*)(smem + BUF0 + tB * 256 + swz(tB, cc * 2)) =
            pack2((kv[c].y - mB) * rB * g0 + b0,
                  (kv[c + 1].y - mB) * rB * g1 + b1);
      }
    }
    {
      float mA, rA, mB, rB;
      ln_stats(vv, mA, rA, mB, rB);
#pragma unroll
      for (int c = 0; c < 32; ++c) {
        int cc = cbase + c;
        float g0 = gkl[cc], b0 = bkl[cc];
        *(u32*)(smem + VOFF + cc * 512 + swz(cc, tA * 2)) =
            pack2((vv[c].x - mA) * rA * g0 + b0,
                  (vv[c].y - mB) * rB * g0 + b0);
      }
    }
  }
  __syncthreads();

  // ---- attention: wave owns q rows [wv*32, wv*32+32); heads paired for ILP.
  // Both heads of a pair share one 4KB P tile (head0 bytes [0,64), head1
  // [64,128) of each 128B row) so the two chains interleave without barriers.
  u32 oPk[8][4];
  const int pbase = POFF + wv * 4096;
#pragma unroll
  for (int hp = 0; hp < 4; ++hp) {
    const int h0 = hp * 2, h1 = h0 + 1;
    f32x4 o00 = {}, o01 = {}, o10 = {}, o11 = {};
    float m0 = -1e30f, l0 = 0.f, m1 = -1e30f, l1 = 0.f;
#pragma unroll 1
    for (int kt = 0; kt < 7; ++kt) {
      float f0 = qk_soft(smem, h0, 0, kt, qf[h0], lane, pbase, m0, l0);
      float f1 = qk_soft(smem, h1, 1, kt, qf[h1], lane, pbase, m1, l1);
      pv_step(smem, h0, 0, kt, lane, pbase, f0, o00, o01);
      pv_step(smem, h1, 1, kt, lane, pbase, f1, o10, o11);
    }
    l0 += __shfl_xor(l0, 32);
    l1 += __shfl_xor(l1, 32);
    float i0 = 1.0f / l0, i1 = 1.0f / l1;
#pragma unroll
    for (int r = 0; r < 4; ++r) {
      o00[r] *= __shfl(i0, (lane >> 4) * 4 + r);
      o01[r] *= __shfl(i0, 16 + (lane >> 4) * 4 + r);
      o10[r] *= __shfl(i1, (lane >> 4) * 4 + r);
      o11[r] *= __shfl(i1, 16 + (lane >> 4) * 4 + r);
    }
    oPk[h0][0] = pack2(o00[0], o00[1]);
    oPk[h0][1] = pack2(o00[2], o00[3]);
    oPk[h0][2] = pack2(o01[0], o01[1]);
    oPk[h0][3] = pack2(o01[2], o01[3]);
    oPk[h1][0] = pack2(o10[0], o10[1]);
    oPk[h1][1] = pack2(o10[2], o10[3]);
    oPk[h1][2] = pack2(o11[0], o11[1]);
    oPk[h1][3] = pack2(o11[2], o11[3]);
  }
  __syncthreads();

  // ---- O -> buf0 [token][ch] bf16 ; proj_w -> VOFF [j][ch] bf16
#pragma unroll
  for (int h = 0; h < 8; ++h) {
#pragma unroll
    for (int j = 0; j < 8; ++j) {
      int qh = j >> 2, r = j & 3;
      int row = wv * 32 + qh * 16 + (lane >> 4) * 4 + r;
      int c = h * 16 + (lane & 15);
      u16 v = (u16)(oPk[h][qh * 2 + (r >> 1)] >> ((r & 1) * 16));
      *(u16*)(smem + BUF0 + row * 256 + swz(row, c * 2)) = v;
    }
  }
  for (int i = tid; i < 8192; i += THREADS) {
    int j = i >> 6, c2 = i & 63;
    f32x2 w2 = *(const f32x2*)(pw + j * 128 + c2 * 2);
    *(u32*)(smem + VOFF + j * 256 + swz(j, c2 * 4)) = pack2(w2.x, w2.y);
  }
  __syncthreads();

  // ---- projection: D[j][token] = W(A) x O(B); wave owns 2 token tiles
#pragma unroll 1
  for (int ti = 0; ti < 2; ++ti) {
    int tt = wv * 2 + ti;
    int tok = tt * 16 + (lane & 15);
    s16x8 bfr[4];
#pragma unroll
    for (int kk = 0; kk < 4; ++kk)
      bfr[kk] = *(const s16x8*)(smem + BUF0 + tok * 256 +
                                swz(tok, kk * 64 + (lane >> 4) * 16));
    bool tokValid = tok < TOK;
    int tdd = tok / 36, trr = tok - tdd * 36;
    int thh = trr / 6, tww = trr - thh * 6;
    int pos = boff + tdd * 2304 + thh * 48 + tww;
#pragma unroll 1
    for (int jt = 0; jt < 8; ++jt) {
      f32x4 acc = {};
#pragma unroll
      for (int kk = 0; kk < 4; ++kk) {
        int rw = jt * 16 + (lane & 15);
        s16x8 af = *(const s16x8*)(smem + VOFF + rw * 256 +
                                   swz(rw, kk * 64 + (lane >> 4) * 16));
        acc = __builtin_amdgcn_mfma_f32_16x16x32_bf16(af, bfr[kk], acc, 0, 0, 0);
      }
      f32x4 pbv = *(const f32x4*)(pb + jt * 16 + (lane >> 4) * 4);
      if (tokValid) {
#pragma unroll
        for (int r = 0; r < 4; ++r) {
          int j = jt * 16 + (lane >> 4) * 4 + r;
          out[j * SP + pos] = acc[r] + pbv[r];
        }
      }
    }
  }
}

extern "C" void kernel_launch(void* const* d_in, const int* in_sizes, int n_in,
                              void* d_out, int out_size, void* d_ws, size_t ws_size,
                              hipStream_t stream) {
  const float* qm  = (const float*)d_in[0];
  const float* km  = (const float*)d_in[1];
  const float* vm  = (const float*)d_in[2];
  const float* gq  = (const float*)d_in[3];
  const float* bq  = (const float*)d_in[4];
  const float* gkv = (const float*)d_in[5];
  const float* bkv = (const float*)d_in[6];
  const float* pw  = (const float*)d_in[7];
  const float* pb  = (const float*)d_in[8];
  hipLaunchKernelGGL(ca3d_kernel, dim3(512), dim3(THREADS), LDS_BYTES, stream,
                     qm, km, vm, gq, bq, gkv, bkv, pw, pb, (float*)d_out);
}

// Round 6
// 170.429 us; speedup vs baseline: 2.2003x; 1.0548x over previous
//
#include <hip/hip_runtime.h>

typedef short s16x8 __attribute__((ext_vector_type(8)));
typedef float f32x2 __attribute__((ext_vector_type(2)));
typedef float f32x4 __attribute__((ext_vector_type(4)));
typedef float f32x16 __attribute__((ext_vector_type(16)));
typedef unsigned int u32;
typedef unsigned short u16;
typedef u32 u32x4v __attribute__((ext_vector_type(4)));

#define TOK 216
#define THREADS 448
#define SP 110592           // 48*48*48
#define BUF0 0              // qb -> kb -> obuf : 224 rows x 256B = 57344
#define VOFF 57344          // vb_t: 128 ch-rows x 512B = 65536
#define WOFF 122880         // proj_w bf16: 128 rows x 256B = 32768
#define GBOFF 155648        // gamma/beta staging: 2048
#define LDS_BYTES 157696

__device__ __forceinline__ u16 f2bf(float f) {
  u32 u = __builtin_bit_cast(u32, f);
  u32 r = u + 0x7FFFu + ((u >> 16) & 1u);
  return (u16)(r >> 16);
}
__device__ __forceinline__ u32 pack2(float a, float b) {
  return (u32)f2bf(a) | ((u32)f2bf(b) << 16);
}
__device__ __forceinline__ int swz(int row, int inner) {
  return inner ^ ((row & 7) << 4);
}

// per token-pair LN stats over 128 ch held as 32 f32x2 across 4 lanes
__device__ __forceinline__ void ln_stats(const f32x2* xv, float& mA, float& rA,
                                         float& mB, float& rB) {
  float sA = 0.f, s2A = 0.f, sB = 0.f, s2B = 0.f;
#pragma unroll
  for (int c = 0; c < 32; ++c) {
    sA += xv[c].x; s2A += xv[c].x * xv[c].x;
    sB += xv[c].y; s2B += xv[c].y * xv[c].y;
  }
  sA += __shfl_xor(sA, 1); s2A += __shfl_xor(s2A, 1);
  sB += __shfl_xor(sB, 1); s2B += __shfl_xor(s2B, 1);
  sA += __shfl_xor(sA, 2); s2A += __shfl_xor(s2A, 2);
  sB += __shfl_xor(sB, 2); s2B += __shfl_xor(s2B, 2);
  mA = sA * (1.0f / 128.0f);
  rA = rsqrtf(s2A * (1.0f / 128.0f) - mA * mA + 1e-5f);
  mB = sB * (1.0f / 128.0f);
  rB = rsqrtf(s2B * (1.0f / 128.0f) - mB * mB + 1e-5f);
}

// One (head, k-tile) step, fully in-register P, verified primitives only:
//   S^T = mfma(K, Q): lane(q=lane&31, half) reg r holds k=(r&3)+8*(r>>2)+4*half
//   online softmax; halves merged via __shfl_xor(.,32)
//   P packed (f2bf) to u32 pairs A[0..7]; cross-half exchange via
//   shfl_xor+select builds B-frags pf0 (k0..15) / pf1 (k16..31)
//   O^T += V^T x P^T; D col = q = lane&31 -> rescale/normalize lane-local.
template<bool MASK>
__device__ __forceinline__ void attn_step(const char* smem, int h, int kt,
                                          s16x8 qfh, int lane,
                                          f32x16& acc, float& m, float& lsum) {
  const int half = lane >> 5;
  const int krow = kt * 32 + (lane & 31);
  s16x8 kf = *(const s16x8*)(smem + BUF0 + krow * 256 +
                             swz(krow, h * 32 + half * 16));
  __builtin_amdgcn_s_setprio(1);
  f32x16 st = __builtin_amdgcn_mfma_f32_32x32x16_bf16(kf, qfh, (f32x16){}, 0, 0, 0);
  __builtin_amdgcn_s_setprio(0);
  const int NR = MASK ? 12 : 16;   // kt=6: k-local>=24 <=> r>=12 (both halves)
  float mx = st[0];
#pragma unroll
  for (int r = 1; r < NR; ++r) mx = fmaxf(mx, st[r]);
  mx = fmaxf(mx, __shfl_xor(mx, 32));   // merge halves (same q row)
  float mn = fmaxf(m, mx);
  float fct = __expf(m - mn);
  m = mn;
  u32 A[8];
  float ts = 0.f;
#pragma unroll
  for (int i = 0; i < 8; ++i) {
    float p0 = (2 * i < NR) ? __expf(st[2 * i] - mn) : 0.f;
    float p1 = (2 * i + 1 < NR) ? __expf(st[2 * i + 1] - mn) : 0.f;
    ts += p0 + p1;
    A[i] = pack2(p0, p1);
  }
  lsum = lsum * fct + (ts + __shfl_xor(ts, 32));
#pragma unroll
  for (int r = 0; r < 8; ++r) acc[r] *= fct;   // q lane-local; r>=8 unused dups
  // A[i] k-pairs: half0 {0,1}{2,3}{8,9}{10,11}{16,17}{18,19}{24,25}{26,27},
  //               half1 = +4. B-frag slot j of lane(q,half) needs k=half*8+j
  // (pf0) and 16+half*8+j (pf1). Exchange: half0 needs half1's A0,A1 (k4..7);
  // half1 needs half0's A2,A3 (k8..11). One shfl_xor serves both directions.
  u32 S0 = half ? A[0] : A[2], S1 = half ? A[1] : A[3];
  u32 S2 = half ? A[4] : A[6], S3 = half ? A[5] : A[7];
  u32 E0 = __shfl_xor(S0, 32), E1 = __shfl_xor(S1, 32);
  u32 E2 = __shfl_xor(S2, 32), E3 = __shfl_xor(S3, 32);
  s16x8 pf0 = __builtin_bit_cast(s16x8, (u32x4v){
      half ? E0 : A[0], half ? E1 : A[1], half ? A[2] : E0, half ? A[3] : E1});
  s16x8 pf1 = __builtin_bit_cast(s16x8, (u32x4v){
      half ? E2 : A[4], half ? E3 : A[5], half ? A[6] : E2, half ? A[7] : E3});
  const int vrow = h * 16 + (lane & 15);  // A rows 16-31 duplicate (D rows unused)
  s16x8 vf0 = *(const s16x8*)(smem + VOFF + vrow * 512 +
                              swz(vrow, kt * 64 + half * 16));
  s16x8 vf1 = *(const s16x8*)(smem + VOFF + vrow * 512 +
                              swz(vrow, kt * 64 + 32 + half * 16));
  __builtin_amdgcn_s_setprio(1);
  acc = __builtin_amdgcn_mfma_f32_32x32x16_bf16(vf0, pf0, acc, 0, 0, 0);
  acc = __builtin_amdgcn_mfma_f32_32x32x16_bf16(vf1, pf1, acc, 0, 0, 0);
  __builtin_amdgcn_s_setprio(0);
}

extern "C" __global__ __launch_bounds__(THREADS, 2)
void ca3d_kernel(const float* __restrict__ qm, const float* __restrict__ km,
                 const float* __restrict__ vm,
                 const float* __restrict__ gq, const float* __restrict__ bq,
                 const float* __restrict__ gkv, const float* __restrict__ bkv,
                 const float* __restrict__ pw, const float* __restrict__ pb,
                 float* __restrict__ out) {
  extern __shared__ __align__(16) char smem[];
  const int tid = threadIdx.x;
  const int lane = tid & 63;
  const int wv = tid >> 6;
  // XCD chunked swizzle: contiguous 64-window chunk per XCD
  const int bid = blockIdx.x;
  const int wid = ((bid & 7) << 6) | (bid >> 3);
  const int wd = wid >> 6, wh = (wid >> 3) & 7, ww = wid & 7;
  const int boff = wd * 6 * 2304 + wh * 6 * 48 + ww * 6;

  // zero qb/kb + vb_t regions (pad rows must be finite/zero)
  for (int i = tid * 16; i < VOFF + 65536; i += THREADS * 16)
    *(f32x4*)(smem + i) = (f32x4){};
  if (tid < 128) {
    ((float*)(smem + GBOFF))[tid] = gq[tid];
    ((float*)(smem + GBOFF + 512))[tid] = bq[tid];
    ((float*)(smem + GBOFF + 1024))[tid] = gkv[tid];
    ((float*)(smem + GBOFF + 1536))[tid] = bkv[tid];
  }

  // LN thread mapping: 432 threads = 108 token-pairs x 4 channel-quadrants
  const bool lnAct = tid < 432;
  const int tp = tid >> 2;
  const int cbase = (tid & 3) * 32;
  const int tA = tp * 2, tB = tA + 1;
  int td = tA / 36, tr_ = tA - td * 36;
  int th_ = tr_ / 6, tw_ = tr_ - th_ * 6;
  const int gpos = boff + td * 2304 + th_ * 48 + tw_;

  f32x2 qv[32], kv[32], vv[32];
  if (lnAct) {
#pragma unroll
    for (int c = 0; c < 32; ++c)
      qv[c] = *(const f32x2*)(qm + gpos + (cbase + c) * SP);
#pragma unroll
    for (int c = 0; c < 32; ++c)
      kv[c] = *(const f32x2*)(km + gpos + (cbase + c) * SP);
  }
  __syncthreads();

  const float* gql = (const float*)(smem + GBOFF);
  const float* bql = (const float*)(smem + GBOFF + 512);
  const float* gkl = (const float*)(smem + GBOFF + 1024);
  const float* bkl = (const float*)(smem + GBOFF + 1536);

  // ---- Q layernorm (scale 0.25 folded) -> buf0 [token][ch]
  if (lnAct) {
    float mA, rA, mB, rB;
    ln_stats(qv, mA, rA, mB, rB);
#pragma unroll
    for (int c = 0; c < 32; c += 2) {
      int cc = cbase + c;
      float g0 = gql[cc], g1 = gql[cc + 1], b0 = bql[cc], b1 = bql[cc + 1];
      *(u32*)(smem + BUF0 + tA * 256 + swz(tA, cc * 2)) =
          pack2(((qv[c].x - mA) * rA * g0 + b0) * 0.25f,
                ((qv[c + 1].x - mA) * rA * g1 + b1) * 0.25f);
      *(u32*)(smem + BUF0 + tB * 256 + swz(tB, cc * 2)) =
          pack2(((qv[c].y - mB) * rB * g0 + b0) * 0.25f,
                ((qv[c + 1].y - mB) * rB * g1 + b1) * 0.25f);
    }
#pragma unroll
    for (int c = 0; c < 32; ++c)
      vv[c] = *(const f32x2*)(vm + gpos + (cbase + c) * SP);
  }
  __syncthreads();

  // ---- Q fragments to registers (B-operand of swapped QK^T)
  s16x8 qf[8];
  {
    int row = wv * 32 + (lane & 31);
    int ib = (lane >> 5) * 16;
#pragma unroll
    for (int h = 0; h < 8; ++h)
      qf[h] = *(const s16x8*)(smem + BUF0 + row * 256 + swz(row, h * 32 + ib));
  }
  __syncthreads();

  // ---- K -> buf0 (overwrite) [token][ch], V -> vb_t [ch][token]
  if (lnAct) {
    {
      float mA, rA, mB, rB;
      ln_stats(kv, mA, rA, mB, rB);
#pragma unroll
      for (int c = 0; c < 32; c += 2) {
        int cc = cbase + c;
        float g0 = gkl[cc], g1 = gkl[cc + 1], b0 = bkl[cc], b1 = bkl[cc + 1];
        *(u32*)(smem + BUF0 + tA * 256 + swz(tA, cc * 2)) =
            pack2((kv[c].x - mA) * rA * g0 + b0,
                  (kv[c + 1].x - mA) * rA * g1 + b1);
        *(u32*)(smem + BUF0 + tB * 256 + swz(tB, cc * 2)) =
            pack2((kv[c].y - mB) * rB * g0 + b0,
                  (kv[c + 1].y - mB) * rB * g1 + b1);
      }
    }
    {
      float mA, rA, mB, rB;
      ln_stats(vv, mA, rA, mB, rB);
#pragma unroll
      for (int c = 0; c < 32; ++c) {
        int cc = cbase + c;
        float g0 = gkl[cc], b0 = bkl[cc];
        *(u32*)(smem + VOFF + cc * 512 + swz(cc, tA * 2)) =
            pack2((vv[c].x - mA) * rA * g0 + b0,
                  (vv[c].y - mB) * rB * g0 + b0);
      }
    }
  }
  // ---- proj_w -> WOFF [j][ch] bf16 (global loads overlap LN compute)
  for (int i = tid; i < 8192; i += THREADS) {
    int j = i >> 6, c2 = i & 63;
    f32x2 w2 = *(const f32x2*)(pw + j * 128 + c2 * 2);
    *(u32*)(smem + WOFF + j * 256 + swz(j, c2 * 4)) = pack2(w2.x, w2.y);
  }
  __syncthreads();

  // ---- attention: wave owns q rows [wv*32, wv*32+32); heads paired for ILP
  u32 oPk[8][4];
#pragma unroll
  for (int hp = 0; hp < 4; ++hp) {
    const int h0 = hp * 2, h1 = h0 + 1;
    f32x16 a0 = {}, a1 = {};
    float m0 = -1e30f, l0 = 0.f, m1 = -1e30f, l1 = 0.f;
#pragma unroll 1
    for (int kt = 0; kt < 6; ++kt) {
      attn_step<false>(smem, h0, kt, qf[h0], lane, a0, m0, l0);
      attn_step<false>(smem, h1, kt, qf[h1], lane, a1, m1, l1);
    }
    attn_step<true>(smem, h0, 6, qf[h0], lane, a0, m0, l0);
    attn_step<true>(smem, h1, 6, qf[h1], lane, a1, m1, l1);
    float i0 = 1.0f / l0, i1 = 1.0f / l1;   // lane-local (l spans both halves)
#pragma unroll
    for (int r = 0; r < 4; ++r) {
      oPk[h0][r] = pack2(a0[2 * r] * i0, a0[2 * r + 1] * i0);
      oPk[h1][r] = pack2(a1[2 * r] * i1, a1[2 * r + 1] * i1);
    }
  }
  __syncthreads();

  // ---- O^T regs -> obuf (BUF0) [token][ch] bf16
  {
    const int tok = wv * 32 + (lane & 31);
    const int half = lane >> 5;
#pragma unroll
    for (int h = 0; h < 8; ++h) {
      // oPk[h][0..3] = head-local ch {e,e+1},{e+2,e+3},{e+8,e+9},{e+10,e+11},
      // e = 4*half; byte offset of ch c is (h*16+c)*2.
      int chb = h * 32 + half * 8;
      *(u32*)(smem + BUF0 + tok * 256 + swz(tok, chb))      = oPk[h][0];
      *(u32*)(smem + BUF0 + tok * 256 + swz(tok, chb + 4))  = oPk[h][1];
      *(u32*)(smem + BUF0 + tok * 256 + swz(tok, chb + 16)) = oPk[h][2];
      *(u32*)(smem + BUF0 + tok * 256 + swz(tok, chb + 20)) = oPk[h][3];
    }
  }
  __syncthreads();

  // ---- projection: D[j][token] = W(A) x O(B); wave owns 2 token tiles
#pragma unroll 1
  for (int ti = 0; ti < 2; ++ti) {
    int tt = wv * 2 + ti;
    int tok = tt * 16 + (lane & 15);
    s16x8 bfr[4];
#pragma unroll
    for (int kk = 0; kk < 4; ++kk)
      bfr[kk] = *(const s16x8*)(smem + BUF0 + tok * 256 +
                                swz(tok, kk * 64 + (lane >> 4) * 16));
    bool tokValid = tok < TOK;
    int tdd = tok / 36, trr = tok - tdd * 36;
    int thh = trr / 6, tww = trr - thh * 6;
    int pos = boff + tdd * 2304 + thh * 48 + tww;
#pragma unroll 1
    for (int jt = 0; jt < 8; ++jt) {
      f32x4 acc = {};
#pragma unroll
      for (int kk = 0; kk < 4; ++kk) {
        int rw = jt * 16 + (lane & 15);
        s16x8 af = *(const s16x8*)(smem + WOFF + rw * 256 +
                                   swz(rw, kk * 64 + (lane >> 4) * 16));
        acc = __builtin_amdgcn_mfma_f32_16x16x32_bf16(af, bfr[kk], acc, 0, 0, 0);
      }
      f32x4 pbv = *(const f32x4*)(pb + jt * 16 + (lane >> 4) * 4);
      if (tokValid) {
#pragma unroll
        for (int r = 0; r < 4; ++r) {
          int j = jt * 16 + (lane >> 4) * 4 + r;
          out[j * SP + pos] = acc[r] + pbv[r];
        }
      }
    }
  }
}

extern "C" void kernel_launch(void* const* d_in, const int* in_sizes, int n_in,
                              void* d_out, int out_size, void* d_ws, size_t ws_size,
                              hipStream_t stream) {
  const float* qm  = (const float*)d_in[0];
  const float* km  = (const float*)d_in[1];
  const float* vm  = (const float*)d_in[2];
  const float* gq  = (const float*)d_in[3];
  const float* bq  = (const float*)d_in[4];
  const float* gkv = (const float*)d_in[5];
  const float* bkv = (const float*)d_in[6];
  const float* pw  = (const float*)d_in[7];
  const float* pb  = (const float*)d_in[8];
  hipLaunchKernelGGL(ca3d_kernel, dim3(512), dim3(THREADS), LDS_BYTES, stream,
                     qm, km, vm, gq, bq, gkv, bkv, pw, pb, (float*)d_out);
}

// Round 7
// 142.253 us; speedup vs baseline: 2.6361x; 1.1981x over previous
//
#include <hip/hip_runtime.h>
#include <hip/hip_bf16.h>

typedef short s16x8 __attribute__((ext_vector_type(8)));
typedef float f32x2 __attribute__((ext_vector_type(2)));
typedef float f32x4 __attribute__((ext_vector_type(4)));
typedef float f32x16 __attribute__((ext_vector_type(16)));
typedef unsigned int u32;
typedef unsigned short u16;
typedef u32 u32x4v __attribute__((ext_vector_type(4)));

#define TOK 216
#define THREADS 448
#define SP 110592           // 48*48*48
#define BUF0 0              // qb -> kb -> obuf : 224 rows x 256B = 57344
#define VOFF 57344          // vb_t: 128 ch-rows x 512B = 65536
#define WOFF 122880         // proj_w bf16: 128 rows x 256B = 32768
#define GBOFF 155648        // gamma/beta staging: 2048
#define LDS_BYTES 157696

// bf16 pack via builtin casts (RNE); compiler fuses to v_cvt_pk_bf16_f32.
// (Hand-written cvt_pk asm is broken -- round 5 vs 6 bisect; m240 agrees.)
__device__ __forceinline__ u32 pack2(float a, float b) {
  u16 lo = __builtin_bit_cast(u16, __float2bfloat16(a));
  u16 hi = __builtin_bit_cast(u16, __float2bfloat16(b));
  return (u32)lo | ((u32)hi << 16);
}
__device__ __forceinline__ int swz(int row, int inner) {
  return inner ^ ((row & 7) << 4);
}

// per token-pair LN stats over 128 ch held as 32 f32x2 across 4 lanes
__device__ __forceinline__ void ln_stats(const f32x2* xv, float& mA, float& rA,
                                         float& mB, float& rB) {
  float sA = 0.f, s2A = 0.f, sB = 0.f, s2B = 0.f;
#pragma unroll
  for (int c = 0; c < 32; ++c) {
    sA += xv[c].x; s2A += xv[c].x * xv[c].x;
    sB += xv[c].y; s2B += xv[c].y * xv[c].y;
  }
  sA += __shfl_xor(sA, 1); s2A += __shfl_xor(s2A, 1);
  sB += __shfl_xor(sB, 1); s2B += __shfl_xor(s2B, 1);
  sA += __shfl_xor(sA, 2); s2A += __shfl_xor(s2A, 2);
  sB += __shfl_xor(sB, 2); s2B += __shfl_xor(s2B, 2);
  mA = sA * (1.0f / 128.0f);
  rA = rsqrtf(s2A * (1.0f / 128.0f) - mA * mA + 1e-5f);
  mB = sB * (1.0f / 128.0f);
  rB = rsqrtf(s2B * (1.0f / 128.0f) - mB * mB + 1e-5f);
}

// One (head, k-tile) step. No-max softmax (shift-invariance; s is bounded ~6
// for LN'ed inputs so exp cannot overflow; p/sum(p) is mathematically exact).
// V is stored with token bits2<->3 swapped per 32-group, so the packed P regs
// A[0..3] / A[4..7] ARE the PV B-fragments directly -- zero cross-lane ops.
template<bool MASK>
__device__ __forceinline__ void attn_step(const char* smem, int h, int kt,
                                          s16x8 qfh, int lane,
                                          f32x16& acc, float& lsum) {
  const int half = lane >> 5;
  const int krow = kt * 32 + (lane & 31);
  s16x8 kf = *(const s16x8*)(smem + BUF0 + krow * 256 +
                             swz(krow, h * 32 + half * 16));
  __builtin_amdgcn_s_setprio(1);
  f32x16 st = __builtin_amdgcn_mfma_f32_32x32x16_bf16(kf, qfh, (f32x16){}, 0, 0, 0);
  __builtin_amdgcn_s_setprio(0);
  // V fragments (independent of st; ds latency hides under exp/pack)
  const int vrow = h * 16 + (lane & 15);  // A rows 16-31 duplicate (D rows unused)
  s16x8 vf0 = *(const s16x8*)(smem + VOFF + vrow * 512 +
                              swz(vrow, kt * 64 + half * 16));
  s16x8 vf1 = *(const s16x8*)(smem + VOFF + vrow * 512 +
                              swz(vrow, kt * 64 + 32 + half * 16));
  const int NR = MASK ? 12 : 16;   // kt=6: k-local>=24 <=> r>=12 (both halves)
  u32 A[8];
  float ts = 0.f;
#pragma unroll
  for (int i = 0; i < 8; ++i) {
    float p0 = (2 * i < NR) ? __expf(st[2 * i]) : 0.f;
    float p1 = (2 * i + 1 < NR) ? __expf(st[2 * i + 1]) : 0.f;
    ts += p0 + p1;
    A[i] = pack2(p0, p1);
  }
  lsum += ts;                      // per-half partial; merged after kt loop
  s16x8 pf0 = __builtin_bit_cast(s16x8, (u32x4v){A[0], A[1], A[2], A[3]});
  s16x8 pf1 = __builtin_bit_cast(s16x8, (u32x4v){A[4], A[5], A[6], A[7]});
  __builtin_amdgcn_s_setprio(1);
  acc = __builtin_amdgcn_mfma_f32_32x32x16_bf16(vf0, pf0, acc, 0, 0, 0);
  acc = __builtin_amdgcn_mfma_f32_32x32x16_bf16(vf1, pf1, acc, 0, 0, 0);
  __builtin_amdgcn_s_setprio(0);
}

extern "C" __global__ __launch_bounds__(THREADS, 2)
void ca3d_kernel(const float* __restrict__ qm, const float* __restrict__ km,
                 const float* __restrict__ vm,
                 const float* __restrict__ gq, const float* __restrict__ bq,
                 const float* __restrict__ gkv, const float* __restrict__ bkv,
                 const float* __restrict__ pw, const float* __restrict__ pb,
                 float* __restrict__ out) {
  extern __shared__ __align__(16) char smem[];
  const int tid = threadIdx.x;
  const int lane = tid & 63;
  const int wv = tid >> 6;
  // XCD chunked swizzle: contiguous 64-window chunk per XCD
  const int bid = blockIdx.x;
  const int wid = ((bid & 7) << 6) | (bid >> 3);
  const int wd = wid >> 6, wh = (wid >> 3) & 7, ww = wid & 7;
  const int boff = wd * 6 * 2304 + wh * 6 * 48 + ww * 6;

  // zero qb/kb + vb_t regions (pad rows/positions must be finite/zero)
  for (int i = tid * 16; i < VOFF + 65536; i += THREADS * 16)
    *(f32x4*)(smem + i) = (f32x4){};
  if (tid < 128) {
    ((float*)(smem + GBOFF))[tid] = gq[tid];
    ((float*)(smem + GBOFF + 512))[tid] = bq[tid];
    ((float*)(smem + GBOFF + 1024))[tid] = gkv[tid];
    ((float*)(smem + GBOFF + 1536))[tid] = bkv[tid];
  }

  // LN thread mapping: 432 threads = 108 token-pairs x 4 channel-quadrants
  const bool lnAct = tid < 432;
  const int tp = tid >> 2;
  const int cbase = (tid & 3) * 32;
  const int tA = tp * 2, tB = tA + 1;
  int td = tA / 36, tr_ = tA - td * 36;
  int th_ = tr_ / 6, tw_ = tr_ - th_ * 6;
  const int gpos = boff + td * 2304 + th_ * 48 + tw_;
  // V store position: swap token bits 2<->3 within each 32-group (sigma).
  // tA even -> vposA even; tB = tA+1 shares the u32.
  const int vposA = (tA & ~0xC) | ((tA & 4) << 1) | ((tA & 8) >> 1);

  f32x2 qv[32], kv[32], vv[32];
  if (lnAct) {
#pragma unroll
    for (int c = 0; c < 32; ++c)
      qv[c] = *(const f32x2*)(qm + gpos + (cbase + c) * SP);
#pragma unroll
    for (int c = 0; c < 32; ++c)
      kv[c] = *(const f32x2*)(km + gpos + (cbase + c) * SP);
  }
  __syncthreads();

  const float* gql = (const float*)(smem + GBOFF);
  const float* bql = (const float*)(smem + GBOFF + 512);
  const float* gkl = (const float*)(smem + GBOFF + 1024);
  const float* bkl = (const float*)(smem + GBOFF + 1536);

  // ---- Q layernorm (scale 0.25 folded) -> buf0 [token][ch]
  if (lnAct) {
    float mA, rA, mB, rB;
    ln_stats(qv, mA, rA, mB, rB);
#pragma unroll
    for (int c = 0; c < 32; c += 2) {
      int cc = cbase + c;
      float g0 = gql[cc], g1 = gql[cc + 1], b0 = bql[cc], b1 = bql[cc + 1];
      *(u32*)(smem + BUF0 + tA * 256 + swz(tA, cc * 2)) =
          pack2(((qv[c].x - mA) * rA * g0 + b0) * 0.25f,
                ((qv[c + 1].x - mA) * rA * g1 + b1) * 0.25f);
      *(u32*)(smem + BUF0 + tB * 256 + swz(tB, cc * 2)) =
          pack2(((qv[c].y - mB) * rB * g0 + b0) * 0.25f,
                ((qv[c + 1].y - mB) * rB * g1 + b1) * 0.25f);
    }
#pragma unroll
    for (int c = 0; c < 32; ++c)
      vv[c] = *(const f32x2*)(vm + gpos + (cbase + c) * SP);
  }
  __syncthreads();

  // ---- Q fragments to registers (B-operand of swapped QK^T)
  s16x8 qf[8];
  {
    int row = wv * 32 + (lane & 31);
    int ib = (lane >> 5) * 16;
#pragma unroll
    for (int h = 0; h < 8; ++h)
      qf[h] = *(const s16x8*)(smem + BUF0 + row * 256 + swz(row, h * 32 + ib));
  }
  __syncthreads();

  // ---- K -> buf0 (overwrite) [token][ch], V -> vb_t [ch][sigma(token)]
  if (lnAct) {
    {
      float mA, rA, mB, rB;
      ln_stats(kv, mA, rA, mB, rB);
#pragma unroll
      for (int c = 0; c < 32; c += 2) {
        int cc = cbase + c;
        float g0 = gkl[cc], g1 = gkl[cc + 1], b0 = bkl[cc], b1 = bkl[cc + 1];
        *(u32*)(smem + BUF0 + tA * 256 + swz(tA, cc * 2)) =
            pack2((kv[c].x - mA) * rA * g0 + b0,
                  (kv[c + 1].x - mA) * rA * g1 + b1);
        *(u32*)(smem + BUF0 + tB * 256 + swz(tB, cc * 2)) =
            pack2((kv[c].y - mB) * rB * g0 + b0,
                  (kv[c + 1].y - mB) * rB * g1 + b1);
      }
    }
    {
      float mA, rA, mB, rB;
      ln_stats(vv, mA, rA, mB, rB);
#pragma unroll
      for (int c = 0; c < 32; ++c) {
        int cc = cbase + c;
        float g0 = gkl[cc], b0 = bkl[cc];
        *(u32*)(smem + VOFF + cc * 512 + swz(cc, vposA * 2)) =
            pack2((vv[c].x - mA) * rA * g0 + b0,
                  (vv[c].y - mB) * rB * g0 + b0);
      }
    }
  }
  // ---- proj_w -> WOFF [j][ch] bf16 (global loads overlap LN compute)
  for (int i = tid; i < 8192; i += THREADS) {
    int j = i >> 6, c2 = i & 63;
    f32x2 w2 = *(const f32x2*)(pw + j * 128 + c2 * 2);
    *(u32*)(smem + WOFF + j * 256 + swz(j, c2 * 4)) = pack2(w2.x, w2.y);
  }
  __syncthreads();

  // ---- attention: wave owns q rows [wv*32, wv*32+32); heads paired for ILP
  u32 oPk[8][4];
#pragma unroll
  for (int hp = 0; hp < 4; ++hp) {
    const int h0 = hp * 2, h1 = h0 + 1;
    f32x16 a0 = {}, a1 = {};
    float l0 = 0.f, l1 = 0.f;
#pragma unroll 1
    for (int kt = 0; kt < 6; ++kt) {
      attn_step<false>(smem, h0, kt, qf[h0], lane, a0, l0);
      attn_step<false>(smem, h1, kt, qf[h1], lane, a1, l1);
    }
    attn_step<true>(smem, h0, 6, qf[h0], lane, a0, l0);
    attn_step<true>(smem, h1, 6, qf[h1], lane, a1, l1);
    l0 += __shfl_xor(l0, 32);               // merge halves once
    l1 += __shfl_xor(l1, 32);
    float i0 = 1.0f / l0, i1 = 1.0f / l1;   // lane-local (col q = lane&31)
#pragma unroll
    for (int r = 0; r < 4; ++r) {
      oPk[h0][r] = pack2(a0[2 * r] * i0, a0[2 * r + 1] * i0);
      oPk[h1][r] = pack2(a1[2 * r] * i1, a1[2 * r + 1] * i1);
    }
  }
  __syncthreads();

  // ---- O^T regs -> obuf (BUF0) [token][ch] bf16
  {
    const int tok = wv * 32 + (lane & 31);
    const int half = lane >> 5;
#pragma unroll
    for (int h = 0; h < 8; ++h) {
      // oPk[h][0..3] = head-local ch {e,e+1},{e+2,e+3},{e+8,e+9},{e+10,e+11},
      // e = 4*half; byte offset of ch c is (h*16+c)*2.
      int chb = h * 32 + half * 8;
      *(u32*)(smem + BUF0 + tok * 256 + swz(tok, chb))      = oPk[h][0];
      *(u32*)(smem + BUF0 + tok * 256 + swz(tok, chb + 4))  = oPk[h][1];
      *(u32*)(smem + BUF0 + tok * 256 + swz(tok, chb + 16)) = oPk[h][2];
      *(u32*)(smem + BUF0 + tok * 256 + swz(tok, chb + 20)) = oPk[h][3];
    }
  }
  __syncthreads();

  // ---- projection: D[j][token] = W(A) x O(B); wave owns 2 token tiles
#pragma unroll 1
  for (int ti = 0; ti < 2; ++ti) {
    int tt = wv * 2 + ti;
    int tok = tt * 16 + (lane & 15);
    s16x8 bfr[4];
#pragma unroll
    for (int kk = 0; kk < 4; ++kk)
      bfr[kk] = *(const s16x8*)(smem + BUF0 + tok * 256 +
                                swz(tok, kk * 64 + (lane >> 4) * 16));
    bool tokValid = tok < TOK;
    int tdd = tok / 36, trr = tok - tdd * 36;
    int thh = trr / 6, tww = trr - thh * 6;
    int pos = boff + tdd * 2304 + thh * 48 + tww;
#pragma unroll 1
    for (int jt = 0; jt < 8; ++jt) {
      f32x4 acc = {};
#pragma unroll
      for (int kk = 0; kk < 4; ++kk) {
        int rw = jt * 16 + (lane & 15);
        s16x8 af = *(const s16x8*)(smem + WOFF + rw * 256 +
                                   swz(rw, kk * 64 + (lane >> 4) * 16));
        acc = __builtin_amdgcn_mfma_f32_16x16x32_bf16(af, bfr[kk], acc, 0, 0, 0);
      }
      f32x4 pbv = *(const f32x4*)(pb + jt * 16 + (lane >> 4) * 4);
      if (tokValid) {
#pragma unroll
        for (int r = 0; r < 4; ++r) {
          int j = jt * 16 + (lane >> 4) * 4 + r;
          out[j * SP + pos] = acc[r] + pbv[r];
        }
      }
    }
  }
}

extern "C" void kernel_launch(void* const* d_in, const int* in_sizes, int n_in,
                              void* d_out, int out_size, void* d_ws, size_t ws_size,
                              hipStream_t stream) {
  const float* qm  = (const float*)d_in[0];
  const float* km  = (const float*)d_in[1];
  const float* vm  = (const float*)d_in[2];
  const float* gq  = (const float*)d_in[3];
  const float* bq  = (const float*)d_in[4];
  const float* gkv = (const float*)d_in[5];
  const float* bkv = (const float*)d_in[6];
  const float* pw  = (const float*)d_in[7];
  const float* pb  = (const float*)d_in[8];
  hipLaunchKernelGGL(ca3d_kernel, dim3(512), dim3(THREADS), LDS_BYTES, stream,
                     qm, km, vm, gq, bq, gkv, bkv, pw, pb, (float*)d_out);
}